// Round 1
// baseline (806.344 us; speedup 1.0000x reference)
//
#include <hip/hip_runtime.h>

#define N_CELLS 8388608
#define N_HALO  1048576

// One thread per halo element e:
//   - load src_idx[e] (int2), weights[e] (float2)
//   - gather 12 raw field values at cell i0 (and i1 iff w1 != 0)
//   - compute the 11 derived quantities per cell, blend, store q-major.
__global__ __launch_bounds__(256) void halo_gather_kernel(
    const float* __restrict__ fields,   // [12][N_CELLS]
    const int2*  __restrict__ src_idx,  // [N_HALO] pairs
    const float2* __restrict__ weights, // [N_HALO] pairs
    float* __restrict__ out)            // [11][N_HALO]
{
    const int e = blockIdx.x * blockDim.x + threadIdx.x;
    if (e >= N_HALO) return;

    const int2   ij = src_idx[e];
    const float2 wv = weights[e];

    const size_t i0 = (size_t)ij.x;
    const size_t i1 = (size_t)ij.y;

    float a[12];
    float b[12];

    // Gather all 12 raw rows at cell i0 (always needed).
    #pragma unroll
    for (int q = 0; q < 12; ++q)
        a[q] = fields[(size_t)q * N_CELLS + i0];

    // Second cell only contributes when w1 != 0 (~50% of elements).
    // Divergent-if: masked lanes issue no memory requests.
    #pragma unroll
    for (int q = 0; q < 12; ++q) b[q] = 0.0f;
    if (wv.y != 0.0f) {
        #pragma unroll
        for (int q = 0; q < 12; ++q)
            b[q] = fields[(size_t)q * N_CELLS + i1];
    }

    const float w0 = wv.x, w1 = wv.y;

    // derived rows (per reference):
    // 0:u 1:v 2:b_u 3:b_v 4:h 5:hh 6:dif_h 7:h+Hb 8:eta1 9:min(k_u,k3) 10:min(k_v,k3)
    float r[11];
    r[0]  = a[0] * w0 + b[0] * w1;
    r[1]  = a[1] * w0 + b[1] * w1;
    r[2]  = a[2] * w0 + b[2] * w1;
    r[3]  = a[3] * w0 + b[3] * w1;
    r[4]  = a[4] * w0 + b[4] * w1;
    r[5]  = a[6] * w0 + b[6] * w1;                          // hh
    r[6]  = a[7] * w0 + b[7] * w1;                          // dif_h
    r[7]  = (a[4] + a[5]) * w0 + (b[4] + b[5]) * w1;        // h + Hb
    r[8]  = a[8] * w0 + b[8] * w1;                          // eta1
    r[9]  = fminf(a[9],  a[11]) * w0 + fminf(b[9],  b[11]) * w1;  // min(k_u,k3)
    r[10] = fminf(a[10], a[11]) * w0 + fminf(b[10], b[11]) * w1;  // min(k_v,k3)

    #pragma unroll
    for (int q = 0; q < 11; ++q)
        out[(size_t)q * N_HALO + e] = r[q];
}

extern "C" void kernel_launch(void* const* d_in, const int* in_sizes, int n_in,
                              void* d_out, int out_size, void* d_ws, size_t ws_size,
                              hipStream_t stream) {
    const float*  fields  = (const float*)d_in[0];
    const int2*   src_idx = (const int2*)d_in[1];
    const float2* weights = (const float2*)d_in[2];
    float* out = (float*)d_out;

    const int block = 256;
    const int grid  = (N_HALO + block - 1) / block;
    halo_gather_kernel<<<grid, block, 0, stream>>>(fields, src_idx, weights, out);
}

// Round 2
// 788.443 us; speedup vs baseline: 1.0227x; 1.0227x over previous
//
#include <hip/hip_runtime.h>

#define N_CELLS 8388608
#define N_HALO  1048576

// Pass structure: 4 kernels, each gathering from only 3 field rows so the
// per-pass working set (3×32 MB rows + 16 MB idx/weights) fits in the 256 MB
// L3. The ~2.9 references per cache line then hit L3 after first touch,
// cutting HBM fetch from "every ref misses" (1.18 GB) to first-touch floor
// (~31 MB/row → ~0.4 GB total).

__device__ __forceinline__ void load_pair(const float* __restrict__ row,
                                          size_t i0, size_t i1, bool has2,
                                          float& a, float& b) {
    a = row[i0];
    b = has2 ? row[i1] : 0.0f;
}

// Group 1: rows u(0), v(1), b_u(2) -> out rows 0,1,2
__global__ __launch_bounds__(256) void g1(
    const float* __restrict__ fields, const int2* __restrict__ src_idx,
    const float2* __restrict__ weights, float* __restrict__ out)
{
    const int e = blockIdx.x * blockDim.x + threadIdx.x;
    if (e >= N_HALO) return;
    const int2 ij = src_idx[e];
    const float2 wv = weights[e];
    const size_t i0 = (size_t)ij.x, i1 = (size_t)ij.y;
    const bool has2 = (wv.y != 0.0f);
    float a0,b0,a1,b1,a2,b2;
    load_pair(fields + 0ull*N_CELLS, i0, i1, has2, a0, b0);
    load_pair(fields + 1ull*N_CELLS, i0, i1, has2, a1, b1);
    load_pair(fields + 2ull*N_CELLS, i0, i1, has2, a2, b2);
    out[0ull*N_HALO + e] = a0*wv.x + b0*wv.y;
    out[1ull*N_HALO + e] = a1*wv.x + b1*wv.y;
    out[2ull*N_HALO + e] = a2*wv.x + b2*wv.y;
}

// Group 2: rows b_v(3), h(4), Hb(5) -> out rows 3 (b_v), 4 (h), 7 (h+Hb)
__global__ __launch_bounds__(256) void g2(
    const float* __restrict__ fields, const int2* __restrict__ src_idx,
    const float2* __restrict__ weights, float* __restrict__ out)
{
    const int e = blockIdx.x * blockDim.x + threadIdx.x;
    if (e >= N_HALO) return;
    const int2 ij = src_idx[e];
    const float2 wv = weights[e];
    const size_t i0 = (size_t)ij.x, i1 = (size_t)ij.y;
    const bool has2 = (wv.y != 0.0f);
    float a3,b3,a4,b4,a5,b5;
    load_pair(fields + 3ull*N_CELLS, i0, i1, has2, a3, b3);
    load_pair(fields + 4ull*N_CELLS, i0, i1, has2, a4, b4);
    load_pair(fields + 5ull*N_CELLS, i0, i1, has2, a5, b5);
    out[3ull*N_HALO + e] = a3*wv.x + b3*wv.y;
    out[4ull*N_HALO + e] = a4*wv.x + b4*wv.y;
    out[7ull*N_HALO + e] = (a4 + a5)*wv.x + (b4 + b5)*wv.y;
}

// Group 3: rows hh(6), dif_h(7), eta1(8) -> out rows 5 (hh), 6 (dif_h), 8 (eta1)
__global__ __launch_bounds__(256) void g3(
    const float* __restrict__ fields, const int2* __restrict__ src_idx,
    const float2* __restrict__ weights, float* __restrict__ out)
{
    const int e = blockIdx.x * blockDim.x + threadIdx.x;
    if (e >= N_HALO) return;
    const int2 ij = src_idx[e];
    const float2 wv = weights[e];
    const size_t i0 = (size_t)ij.x, i1 = (size_t)ij.y;
    const bool has2 = (wv.y != 0.0f);
    float a6,b6,a7,b7,a8,b8;
    load_pair(fields + 6ull*N_CELLS, i0, i1, has2, a6, b6);
    load_pair(fields + 7ull*N_CELLS, i0, i1, has2, a7, b7);
    load_pair(fields + 8ull*N_CELLS, i0, i1, has2, a8, b8);
    out[5ull*N_HALO + e] = a6*wv.x + b6*wv.y;
    out[6ull*N_HALO + e] = a7*wv.x + b7*wv.y;
    out[8ull*N_HALO + e] = a8*wv.x + b8*wv.y;
}

// Group 4: rows k_u(9), k_v(10), k3(11) -> out rows 9 (min(k_u,k3)), 10 (min(k_v,k3))
__global__ __launch_bounds__(256) void g4(
    const float* __restrict__ fields, const int2* __restrict__ src_idx,
    const float2* __restrict__ weights, float* __restrict__ out)
{
    const int e = blockIdx.x * blockDim.x + threadIdx.x;
    if (e >= N_HALO) return;
    const int2 ij = src_idx[e];
    const float2 wv = weights[e];
    const size_t i0 = (size_t)ij.x, i1 = (size_t)ij.y;
    const bool has2 = (wv.y != 0.0f);
    float a9,b9,a10,b10,a11,b11;
    load_pair(fields +  9ull*N_CELLS, i0, i1, has2, a9,  b9);
    load_pair(fields + 10ull*N_CELLS, i0, i1, has2, a10, b10);
    load_pair(fields + 11ull*N_CELLS, i0, i1, has2, a11, b11);
    out[ 9ull*N_HALO + e] = fminf(a9,  a11)*wv.x + fminf(b9,  b11)*wv.y;
    out[10ull*N_HALO + e] = fminf(a10, a11)*wv.x + fminf(b10, b11)*wv.y;
}

extern "C" void kernel_launch(void* const* d_in, const int* in_sizes, int n_in,
                              void* d_out, int out_size, void* d_ws, size_t ws_size,
                              hipStream_t stream) {
    const float*  fields  = (const float*)d_in[0];
    const int2*   src_idx = (const int2*)d_in[1];
    const float2* weights = (const float2*)d_in[2];
    float* out = (float*)d_out;

    const int block = 256;
    const int grid  = (N_HALO + block - 1) / block;
    g1<<<grid, block, 0, stream>>>(fields, src_idx, weights, out);
    g2<<<grid, block, 0, stream>>>(fields, src_idx, weights, out);
    g3<<<grid, block, 0, stream>>>(fields, src_idx, weights, out);
    g4<<<grid, block, 0, stream>>>(fields, src_idx, weights, out);
}

// Round 3
// 759.063 us; speedup vs baseline: 1.0623x; 1.0387x over previous
//
#include <hip/hip_runtime.h>

#define N_CELLS 8388608
#define N_HALO  1048576
#define STRIDE  16   // floats per cell in packed layout: 64 B = one cache line

// Phase 1: streaming transpose+derive. fields[12][N_CELLS] row-major ->
// ws[N_CELLS][16] cell-major (11 derived values + pad to a full 64-B line).
// Reads fully coalesced (consecutive threads, consecutive cells); writes are
// 4x dwordx4 per thread over a contiguous 4 KB span per wave (L2 combines).
__global__ __launch_bounds__(256) void pack_kernel(
    const float* __restrict__ fields, float* __restrict__ ws)
{
    const int c = blockIdx.x * blockDim.x + threadIdx.x;
    if (c >= N_CELLS) return;

    float f[12];
    #pragma unroll
    for (int q = 0; q < 12; ++q)
        f[q] = fields[(size_t)q * N_CELLS + c];

    // derived order = output row order:
    // 0:u 1:v 2:b_u 3:b_v 4:h 5:hh 6:dif_h 7:h+Hb 8:eta1 9:min(k_u,k3) 10:min(k_v,k3)
    float4* o = (float4*)(ws + (size_t)c * STRIDE);
    o[0] = make_float4(f[0], f[1], f[2], f[3]);
    o[1] = make_float4(f[4], f[6], f[7], f[4] + f[5]);
    o[2] = make_float4(f[8], fminf(f[9], f[11]), fminf(f[10], f[11]), 0.0f);
    o[3] = make_float4(0.0f, 0.0f, 0.0f, 0.0f);  // complete the 64-B line (no sector RMW)
}

// Phase 2: per halo element, gather one 64-B line per source cell
// (3x float4), blend, store q-major coalesced.
__global__ __launch_bounds__(256) void gather_kernel(
    const float* __restrict__ ws, const int2* __restrict__ src_idx,
    const float2* __restrict__ weights, float* __restrict__ out)
{
    const int e = blockIdx.x * blockDim.x + threadIdx.x;
    if (e >= N_HALO) return;

    const int2   ij = src_idx[e];
    const float2 wv = weights[e];

    const float4* p0 = (const float4*)(ws + (size_t)ij.x * STRIDE);
    float4 a0 = p0[0], a1 = p0[1], a2 = p0[2];

    float4 b0 = make_float4(0,0,0,0), b1 = b0, b2 = b0;
    if (wv.y != 0.0f) {  // ~50% of elements have no second source
        const float4* p1 = (const float4*)(ws + (size_t)ij.y * STRIDE);
        b0 = p1[0]; b1 = p1[1]; b2 = p1[2];
    }

    const float w0 = wv.x, w1 = wv.y;
    out[0ull*N_HALO + e]  = a0.x*w0 + b0.x*w1;  // u
    out[1ull*N_HALO + e]  = a0.y*w0 + b0.y*w1;  // v
    out[2ull*N_HALO + e]  = a0.z*w0 + b0.z*w1;  // b_u
    out[3ull*N_HALO + e]  = a0.w*w0 + b0.w*w1;  // b_v
    out[4ull*N_HALO + e]  = a1.x*w0 + b1.x*w1;  // h
    out[5ull*N_HALO + e]  = a1.y*w0 + b1.y*w1;  // hh
    out[6ull*N_HALO + e]  = a1.z*w0 + b1.z*w1;  // dif_h
    out[7ull*N_HALO + e]  = a1.w*w0 + b1.w*w1;  // h+Hb
    out[8ull*N_HALO + e]  = a2.x*w0 + b2.x*w1;  // eta1
    out[9ull*N_HALO + e]  = a2.y*w0 + b2.y*w1;  // min(k_u,k3)
    out[10ull*N_HALO + e] = a2.z*w0 + b2.z*w1;  // min(k_v,k3)
}

extern "C" void kernel_launch(void* const* d_in, const int* in_sizes, int n_in,
                              void* d_out, int out_size, void* d_ws, size_t ws_size,
                              hipStream_t stream) {
    const float*  fields  = (const float*)d_in[0];
    const int2*   src_idx = (const int2*)d_in[1];
    const float2* weights = (const float2*)d_in[2];
    float* out = (float*)d_out;
    float* ws  = (float*)d_ws;  // needs N_CELLS*16*4 = 512 MB (ws_size ~1.6 GB per fill counters)

    const int block = 256;
    pack_kernel  <<<(N_CELLS + block - 1) / block, block, 0, stream>>>(fields, ws);
    gather_kernel<<<(N_HALO  + block - 1) / block, block, 0, stream>>>(ws, src_idx, weights, out);
}